// Round 2
// baseline (17.332 us; speedup 1.0000x reference)
//
#include <hip/hip_runtime.h>

// Problem constants (from reference)
#define X_AXIS 32
#define Y_AXIS 32
#define F_DIM  64
#define N_NODES (X_AXIS * Y_AXIS)   // 1024

// Mathematical reduction (see R0):
//   softmax over axis 0 sums to 1; node is constant along axis 0
//   => out2d[x,y] = sum_f W_out[f,x,y] * h[f,x,y]
//   adj / W_pair / a_pair are algebraically dead.
//
// R1: float4 vectorization — 4 cells per thread, 16 B/lane loads.
// 4 blocks x 64 threads covers all 1024 cells (4*64*4 = 1024).

__global__ void MyGAT_reduced_v2(const float4* __restrict__ h4,
                                 const float4* __restrict__ W4,
                                 float4* __restrict__ out4) {
    const int q = blockIdx.x * blockDim.x + threadIdx.x;  // float4 index: cells 4q..4q+3
    float4 acc = make_float4(0.f, 0.f, 0.f, 0.f);
#pragma unroll
    for (int f = 0; f < F_DIM; ++f) {
        // [F][1024] layout -> float4 stride of 256 per f step.
        const float4 a = h4[f * (N_NODES / 4) + q];
        const float4 b = W4[f * (N_NODES / 4) + q];
        acc.x = fmaf(a.x, b.x, acc.x);
        acc.y = fmaf(a.y, b.y, acc.y);
        acc.z = fmaf(a.z, b.z, acc.z);
        acc.w = fmaf(a.w, b.w, acc.w);
    }
    out4[q] = acc;
}

extern "C" void kernel_launch(void* const* d_in, const int* in_sizes, int n_in,
                              void* d_out, int out_size, void* d_ws, size_t ws_size,
                              hipStream_t stream) {
    // setup_inputs() order: h, adj, W_pair, a_pair, W_out
    const float4* h4 = (const float4*)d_in[0];
    const float4* W4 = (const float4*)d_in[4];
    float4* out4 = (float4*)d_out;

    // 4 blocks x 64 threads, 4 cells per thread.
    MyGAT_reduced_v2<<<4, 64, 0, stream>>>(h4, W4, out4);
}

// Round 3
// 13.121 us; speedup vs baseline: 1.3210x; 1.3210x over previous
//
#include <hip/hip_runtime.h>

// Problem constants (from reference)
#define X_AXIS 32
#define Y_AXIS 32
#define F_DIM  64
#define N_NODES (X_AXIS * Y_AXIS)   // 1024

// Mathematical reduction (see R0):
//   att = softmax(attx, axis=0)  =>  sum_x att[x,y] == 1 for all y
//   node has shape (1,N) -> constant along axis 0
//   out[y] = sum_x node[y]*att[x,y] = node[y]
//   => out2d[x,y] = sum_f W_out[f,x,y] * h[f,x,y]
//   adj / W_pair / a_pair are algebraically dead.
//
// R2: repeatability A/B — this is byte-for-byte the R0 kernel (12.9 µs),
// resubmitted to measure session-to-session noise of the launch-overhead
// floor vs R1's 17.3 µs. Kernel-resident time is provably sub-µs
// (512 KB L2-warm read), so dur_us here is the replay overhead floor.

__global__ void MyGAT_reduced_kernel(const float* __restrict__ h,
                                     const float* __restrict__ W_out,
                                     float* __restrict__ out) {
    const int c = blockIdx.x * blockDim.x + threadIdx.x;  // cell = x*32 + y
    if (c >= N_NODES) return;
    float acc = 0.0f;
#pragma unroll
    for (int f = 0; f < F_DIM; ++f) {
        // h, W_out both laid out [F][X][Y] contiguously: offset f*1024 + c.
        // Consecutive threads -> consecutive addresses at each f: coalesced.
        acc = fmaf(h[f * N_NODES + c], W_out[f * N_NODES + c], acc);
    }
    out[c] = acc;
}

extern "C" void kernel_launch(void* const* d_in, const int* in_sizes, int n_in,
                              void* d_out, int out_size, void* d_ws, size_t ws_size,
                              hipStream_t stream) {
    // setup_inputs() order: h, adj, W_pair, a_pair, W_out
    const float* h     = (const float*)d_in[0];
    // d_in[1] adj, d_in[2] W_pair, d_in[3] a_pair: unused (dead path)
    const float* W_out = (const float*)d_in[4];
    float* out = (float*)d_out;

    MyGAT_reduced_kernel<<<(N_NODES + 255) / 256, 256, 0, stream>>>(h, W_out, out);
}